// Round 10
// baseline (295.061 us; speedup 1.0000x reference)
//
#include <hip/hip_runtime.h>

#define D 128
#define SCAN_ELEMS 1024   // elements per scan1 block (256 thr x 4)

typedef __attribute__((ext_vector_type(8))) __bf16 bf16x8;
typedef __attribute__((ext_vector_type(4))) __bf16 bf16x4;
typedef __attribute__((ext_vector_type(2))) __bf16 bf16x2;
typedef __attribute__((ext_vector_type(4))) float  f32x4;

// ---------------------------------------------------------------------------
// wprep: wt[m][col][k] = (bf16) W_m[k][col]   (m: 0,1 = Wv types; 2,3 = Wa)
// 4 x 128 x 128 bf16 = 128 KB, L2/L3-resident.
// ---------------------------------------------------------------------------
__global__ __launch_bounds__(256) void wprep_kernel(
    const float* __restrict__ Wv, const float* __restrict__ Wa,
    __bf16* __restrict__ wt)
{
    int idx = blockIdx.x * 256 + threadIdx.x;    // 0..65535
    int m   = idx >> 14;
    int col = (idx >> 7) & 127;
    int k   = idx & 127;
    const float* src = (m < 2) ? Wv + ((size_t)m * 128 + k) * 128 + col
                               : Wa + ((size_t)(m - 2) * 128 + k) * 128 + col;
    wt[idx] = (__bf16)(*src);
}

// ---------------------------------------------------------------------------
// Stage 1: V[r,:] = (bf16) X[r,:] @ W_v[ntype[r]]   (X f32 in, V bf16 out)
// Swapped-operand MFMA (D = Y^T frags: lane = 1 row x 4 cols) + LDS epilogue
// -> fully-coalesced bf16x8 stores (256 B per row, no RMW).
// ---------------------------------------------------------------------------
__global__ __launch_bounds__(256, 4) void typed_mfma_f32_bf16(
    const float* __restrict__ X, const __bf16* __restrict__ WT,
    const int* __restrict__ ntype, __bf16* __restrict__ V, int n)
{
    __shared__ __bf16 lds_v[32 * 136];   // 32-row chunk, +8 bf16 pad per row

    const int tix = threadIdx.x;
    const int w   = tix >> 6;
    const int l   = tix & 63;
    const int l15 = l & 15;
    const int lk  = l >> 4;
    const int bm  = blockIdx.x * 64;

    const int last = (bm + 63 < n) ? bm + 63 : n - 1;
    const int t0   = ntype[bm];
    const int t1   = ntype[last];
    const bool uni = (t0 == t1);

    for (int t = t0; t <= t1; ++t) {
        const __bf16* wb = WT + ((size_t)t << 14);
        bf16x8 wfr[4][2];
        #pragma unroll
        for (int ks = 0; ks < 4; ++ks)
            #pragma unroll
            for (int nf = 0; nf < 2; ++nf) {
                int col = w * 32 + nf * 16 + l15;
                wfr[ks][nf] = *reinterpret_cast<const bf16x8*>(
                    wb + col * 128 + ks * 32 + lk * 8);
            }

        f32x4 acc[4][2];
        #pragma unroll
        for (int rg = 0; rg < 4; ++rg)
            #pragma unroll
            for (int nf = 0; nf < 2; ++nf)
                acc[rg][nf] = (f32x4){0.f, 0.f, 0.f, 0.f};

        #pragma unroll
        for (int rg = 0; rg < 4; ++rg) {
            int row = bm + rg * 16 + l15;
            if (row > n - 1) row = n - 1;
            const float* xr = X + (size_t)row * D + lk * 8;
            #pragma unroll
            for (int ks = 0; ks < 4; ++ks) {
                float4 f0 = *reinterpret_cast<const float4*>(xr + ks * 32);
                float4 f1 = *reinterpret_cast<const float4*>(xr + ks * 32 + 4);
                bf16x8 a;
                a[0] = (__bf16)f0.x; a[1] = (__bf16)f0.y;
                a[2] = (__bf16)f0.z; a[3] = (__bf16)f0.w;
                a[4] = (__bf16)f1.x; a[5] = (__bf16)f1.y;
                a[6] = (__bf16)f1.z; a[7] = (__bf16)f1.w;
                acc[rg][0] = __builtin_amdgcn_mfma_f32_16x16x32_bf16(
                    wfr[ks][0], a, acc[rg][0], 0, 0, 0);
                acc[rg][1] = __builtin_amdgcn_mfma_f32_16x16x32_bf16(
                    wfr[ks][1], a, acc[rg][1], 0, 0, 0);
            }
        }

        #pragma unroll
        for (int ch = 0; ch < 2; ++ch) {
            __syncthreads();
            #pragma unroll
            for (int rh = 0; rh < 2; ++rh) {
                int rg = ch * 2 + rh;
                #pragma unroll
                for (int nf = 0; nf < 2; ++nf) {
                    int rloc = rh * 16 + l15;
                    int c    = w * 32 + nf * 16 + lk * 4;
                    bf16x4 o;
                    o[0] = (__bf16)acc[rg][nf][0];
                    o[1] = (__bf16)acc[rg][nf][1];
                    o[2] = (__bf16)acc[rg][nf][2];
                    o[3] = (__bf16)acc[rg][nf][3];
                    *reinterpret_cast<bf16x4*>(&lds_v[rloc * 136 + c]) = o;
                }
            }
            __syncthreads();
            #pragma unroll
            for (int p = 0; p < 2; ++p) {
                int idx = tix + p * 256;          // 0..511 = 32 rows x 16 col8
                int rr  = idx >> 4;
                int c8  = idx & 15;
                int row = bm + ch * 32 + rr;
                if (row < n && (uni || ntype[row] == t)) {
                    bf16x8 val = *reinterpret_cast<const bf16x8*>(
                        &lds_v[rr * 136 + c8 * 8]);
                    *reinterpret_cast<bf16x8*>(&V[(size_t)row * D + c8 * 8]) = val;
                }
            }
        }
    }
}

// ---------------------------------------------------------------------------
// Stage 3: Y[r,:] = H[r,:] @ W_a[ntype[r]]   (H bf16 in, Y f32 out)
// ---------------------------------------------------------------------------
__global__ __launch_bounds__(256, 4) void typed_mfma_bf16_f32(
    const __bf16* __restrict__ H, const __bf16* __restrict__ WT,
    const int* __restrict__ ntype, float* __restrict__ Y, int n)
{
    __shared__ float lds_y[32 * 132];

    const int tix = threadIdx.x;
    const int w   = tix >> 6;
    const int l   = tix & 63;
    const int l15 = l & 15;
    const int lk  = l >> 4;
    const int bm  = blockIdx.x * 64;

    const int last = (bm + 63 < n) ? bm + 63 : n - 1;
    const int t0   = ntype[bm];
    const int t1   = ntype[last];
    const bool uni = (t0 == t1);

    for (int t = t0; t <= t1; ++t) {
        const __bf16* wb = WT + ((size_t)t << 14);
        bf16x8 wfr[4][2];
        #pragma unroll
        for (int ks = 0; ks < 4; ++ks)
            #pragma unroll
            for (int nf = 0; nf < 2; ++nf) {
                int col = w * 32 + nf * 16 + l15;
                wfr[ks][nf] = *reinterpret_cast<const bf16x8*>(
                    wb + col * 128 + ks * 32 + lk * 8);
            }

        f32x4 acc[4][2];
        #pragma unroll
        for (int rg = 0; rg < 4; ++rg)
            #pragma unroll
            for (int nf = 0; nf < 2; ++nf)
                acc[rg][nf] = (f32x4){0.f, 0.f, 0.f, 0.f};

        #pragma unroll
        for (int rg = 0; rg < 4; ++rg) {
            int row = bm + rg * 16 + l15;
            if (row > n - 1) row = n - 1;
            const __bf16* hr = H + (size_t)row * D + lk * 8;
            #pragma unroll
            for (int ks = 0; ks < 4; ++ks) {
                bf16x8 a = *reinterpret_cast<const bf16x8*>(hr + ks * 32);
                acc[rg][0] = __builtin_amdgcn_mfma_f32_16x16x32_bf16(
                    wfr[ks][0], a, acc[rg][0], 0, 0, 0);
                acc[rg][1] = __builtin_amdgcn_mfma_f32_16x16x32_bf16(
                    wfr[ks][1], a, acc[rg][1], 0, 0, 0);
            }
        }

        #pragma unroll
        for (int ch = 0; ch < 2; ++ch) {
            __syncthreads();
            #pragma unroll
            for (int rh = 0; rh < 2; ++rh) {
                int rg = ch * 2 + rh;
                #pragma unroll
                for (int nf = 0; nf < 2; ++nf) {
                    int rloc = rh * 16 + l15;
                    int c    = w * 32 + nf * 16 + lk * 4;
                    *reinterpret_cast<float4*>(&lds_y[rloc * 132 + c]) =
                        make_float4(acc[rg][nf][0], acc[rg][nf][1],
                                    acc[rg][nf][2], acc[rg][nf][3]);
                }
            }
            __syncthreads();
            #pragma unroll
            for (int p = 0; p < 4; ++p) {
                int idx = tix + p * 256;
                int rr  = idx >> 5;
                int c4  = idx & 31;
                int row = bm + ch * 32 + rr;
                if (row < n && (uni || ntype[row] == t)) {
                    float4 val = *reinterpret_cast<const float4*>(
                        &lds_y[rr * 132 + c4 * 4]);
                    *reinterpret_cast<float4*>(&Y[(size_t)row * D + c4 * 4]) = val;
                }
            }
        }
    }
}

// ---------------------------------------------------------------------------
// Counting sort of edges by dst, then per-node gather-sum (no f32 atomics).
// hist: int4-vectorized dst reads (4x fewer load instructions).
// ---------------------------------------------------------------------------
__global__ __launch_bounds__(256) void hist_kernel(
    const int* __restrict__ dst, int* __restrict__ counts, int ne)
{
    const int tid    = blockIdx.x * blockDim.x + threadIdx.x;
    const int stride = gridDim.x * blockDim.x;
    const int n4     = ne >> 2;
    const int4* d4   = reinterpret_cast<const int4*>(dst);
    for (int i = tid; i < n4; i += stride) {
        int4 d = d4[i];
        atomicAdd(&counts[d.x], 1);
        atomicAdd(&counts[d.y], 1);
        atomicAdd(&counts[d.z], 1);
        atomicAdd(&counts[d.w], 1);
    }
    for (int e = (n4 << 2) + tid; e < ne; e += stride)
        atomicAdd(&counts[dst[e]], 1);
}

__global__ __launch_bounds__(256) void scan1_kernel(
    const int* __restrict__ counts, int* __restrict__ offs,
    int* __restrict__ bsums, int n)
{
    __shared__ int lds[256];
    const int t    = threadIdx.x;
    const int base = blockIdx.x * SCAN_ELEMS + t * 4;

    int c[4]; int sum = 0;
    #pragma unroll
    for (int i = 0; i < 4; ++i) {
        c[i] = (base + i < n) ? counts[base + i] : 0;
        sum += c[i];
    }
    lds[t] = sum;
    __syncthreads();
    for (int off = 1; off < 256; off <<= 1) {
        int x = (t >= off) ? lds[t - off] : 0;
        __syncthreads();
        lds[t] += x;
        __syncthreads();
    }
    int run = (t == 0) ? 0 : lds[t - 1];
    #pragma unroll
    for (int i = 0; i < 4; ++i) {
        if (base + i < n) offs[base + i] = run;
        run += c[i];
    }
    if (t == 255) bsums[blockIdx.x] = lds[255];
}

__global__ __launch_bounds__(256) void scan2_kernel(int* __restrict__ bsums, int nb)
{
    __shared__ int lds[256];
    const int t    = threadIdx.x;
    const int base = t * 4;
    int c[4]; int sum = 0;
    #pragma unroll
    for (int i = 0; i < 4; ++i) {
        c[i] = (base + i < nb) ? bsums[base + i] : 0;
        sum += c[i];
    }
    lds[t] = sum;
    __syncthreads();
    for (int off = 1; off < 256; off <<= 1) {
        int x = (t >= off) ? lds[t - off] : 0;
        __syncthreads();
        lds[t] += x;
        __syncthreads();
    }
    int run = (t == 0) ? 0 : lds[t - 1];
    #pragma unroll
    for (int i = 0; i < 4; ++i) {
        if (base + i < nb) bsums[base + i] = run;
        run += c[i];
    }
}

__global__ __launch_bounds__(256) void scan3_kernel(
    int* __restrict__ offs, int* __restrict__ cursor,
    const int* __restrict__ bsums, int n)
{
    int i = blockIdx.x * blockDim.x + threadIdx.x;
    if (i < n) {
        int o = offs[i] + bsums[i / SCAN_ELEMS];
        offs[i]   = o;
        cursor[i] = o;
    }
}

// ---------------------------------------------------------------------------
// place, XCD-partitioned: blocks with (bid&7)==g own dst range
// [g*rpx, (g+1)*rpx) -> each 64B ssrc line dirtied by ONE XCD's L2
// (verified round 9: place left top-5; WRITE amplification gone).
// ---------------------------------------------------------------------------
__global__ __launch_bounds__(256) void place_kernel(
    const int* __restrict__ src, const int* __restrict__ dst,
    int* __restrict__ cursor, int* __restrict__ ssrc, int ne, int rpx)
{
    const int g     = blockIdx.x & 7;          // XCD group
    const int chunk = blockIdx.x >> 3;
    const int lo    = g * rpx;
    const int hi    = lo + rpx;
    const int stride = (gridDim.x >> 3) * blockDim.x;

    for (int e = chunk * blockDim.x + threadIdx.x; e < ne; e += stride) {
        int d = dst[e];
        if (d >= lo && d < hi) {
            int pos = atomicAdd(&cursor[d], 1);
            ssrc[pos] = src[e];
        }
    }
}

// ---------------------------------------------------------------------------
// gather v2: one wave per node. Lane-parallel index prefetch: one coalesced
// load pulls up to 64 edge srcs into lane registers; inner loop broadcasts
// via __shfl (VALU, no mem) and issues 8 v-row loads back-to-back -> ~2x
// memory-level parallelism vs the round-9 broadcast-load chain.
// ---------------------------------------------------------------------------
__global__ __launch_bounds__(256) void gather_kernel(
    const __bf16* __restrict__ V, const int* __restrict__ offs,
    const int* __restrict__ counts, const int* __restrict__ ssrc,
    __bf16* __restrict__ H, int n)
{
    const int wid  = (int)((blockIdx.x * 256 + threadIdx.x) >> 6);
    const int lane = threadIdx.x & 63;
    if (wid >= n) return;

    const int beg = offs[wid];
    const int cnt = counts[wid];
    const unsigned int* V32 = reinterpret_cast<const unsigned int*>(V);

    float ax = 0.f, ay = 0.f;

    for (int base = 0; base < cnt; base += 64) {
        int rem = cnt - base;
        if (rem > 64) rem = 64;
        // one coalesced load: lane j holds src index of edge base+j
        int sv = (lane < rem) ? ssrc[beg + base + lane] : 0;

        int j = 0;
        for (; j + 7 < rem; j += 8) {
            int s0 = __shfl(sv, j + 0);
            int s1 = __shfl(sv, j + 1);
            int s2 = __shfl(sv, j + 2);
            int s3 = __shfl(sv, j + 3);
            int s4 = __shfl(sv, j + 4);
            int s5 = __shfl(sv, j + 5);
            int s6 = __shfl(sv, j + 6);
            int s7 = __shfl(sv, j + 7);
            unsigned int u0 = V32[(size_t)s0 * 64 + lane];
            unsigned int u1 = V32[(size_t)s1 * 64 + lane];
            unsigned int u2 = V32[(size_t)s2 * 64 + lane];
            unsigned int u3 = V32[(size_t)s3 * 64 + lane];
            unsigned int u4 = V32[(size_t)s4 * 64 + lane];
            unsigned int u5 = V32[(size_t)s5 * 64 + lane];
            unsigned int u6 = V32[(size_t)s6 * 64 + lane];
            unsigned int u7 = V32[(size_t)s7 * 64 + lane];
            ax += __uint_as_float(u0 << 16) + __uint_as_float(u1 << 16)
                + __uint_as_float(u2 << 16) + __uint_as_float(u3 << 16)
                + __uint_as_float(u4 << 16) + __uint_as_float(u5 << 16)
                + __uint_as_float(u6 << 16) + __uint_as_float(u7 << 16);
            ay += __uint_as_float(u0 & 0xffff0000u) + __uint_as_float(u1 & 0xffff0000u)
                + __uint_as_float(u2 & 0xffff0000u) + __uint_as_float(u3 & 0xffff0000u)
                + __uint_as_float(u4 & 0xffff0000u) + __uint_as_float(u5 & 0xffff0000u)
                + __uint_as_float(u6 & 0xffff0000u) + __uint_as_float(u7 & 0xffff0000u);
        }
        for (; j < rem; ++j) {
            int s = __shfl(sv, j);
            unsigned int u = V32[(size_t)s * 64 + lane];
            ax += __uint_as_float(u << 16);
            ay += __uint_as_float(u & 0xffff0000u);
        }
    }

    bf16x2 o;
    o[0] = (__bf16)ax;
    o[1] = (__bf16)ay;
    reinterpret_cast<bf16x2*>(H)[(size_t)wid * 64 + lane] = o;
}

// ---------------------------------------------------------------------------
extern "C" void kernel_launch(void* const* d_in, const int* in_sizes, int n_in,
                              void* d_out, int out_size, void* d_ws, size_t ws_size,
                              hipStream_t stream)
{
    const float* x     = (const float*)d_in[0];
    const int*   ntype = (const int*)d_in[1];
    const int*   src   = (const int*)d_in[2];
    const int*   dst   = (const int*)d_in[3];
    const float* Wv    = (const float*)d_in[4];
    const float* Wa    = (const float*)d_in[5];

    const int n  = in_sizes[0] / D;   // 100000 nodes
    const int ne = in_sizes[2];       // 800000 edges

    // workspace layout (256B-aligned chunks)
    char* ws = (char*)d_ws;
    size_t off = 0;
    auto alloc = [&](size_t bytes) {
        void* p = ws + off;
        off += (bytes + 255) & ~(size_t)255;
        return p;
    };
    __bf16* v      = (__bf16*)alloc((size_t)n * D * sizeof(__bf16));
    __bf16* h      = (__bf16*)alloc((size_t)n * D * sizeof(__bf16));
    __bf16* wt     = (__bf16*)alloc((size_t)4 * 128 * 128 * sizeof(__bf16));
    int*    counts = (int*)   alloc((size_t)n * sizeof(int));
    int*    offs   = (int*)   alloc((size_t)n * sizeof(int));
    int*    cursor = (int*)   alloc((size_t)n * sizeof(int));
    int*    bsums  = (int*)   alloc(1024 * sizeof(int));
    int*    ssrc   = (int*)   alloc((size_t)ne * sizeof(int));

    float* out = (float*)d_out;

    hipMemsetAsync(counts, 0, (size_t)n * sizeof(int), stream);

    // prep: transposed bf16 weights (Wv -> wt[0..1], Wa -> wt[2..3])
    wprep_kernel<<<256, 256, 0, stream>>>(Wv, Wa, wt);

    // stage 1: v = bf16( typed_linear(x, W_v) )
    const int nblk = (n + 63) / 64;
    typed_mfma_f32_bf16<<<nblk, 256, 0, stream>>>(x, wt, ntype, v, n);

    // counting sort of edges by dst
    hist_kernel<<<1024, 256, 0, stream>>>(dst, counts, ne);
    const int nb = (n + SCAN_ELEMS - 1) / SCAN_ELEMS;
    scan1_kernel<<<nb, 256, 0, stream>>>(counts, offs, bsums, n);
    scan2_kernel<<<1, 256, 0, stream>>>(bsums, nb);
    scan3_kernel<<<(n + 255) / 256, 256, 0, stream>>>(offs, cursor, bsums, n);
    const int rpx = (n + 7) / 8;
    place_kernel<<<1024, 256, 0, stream>>>(src, dst, cursor, ssrc, ne, rpx);

    // stage 2: h = bf16( segment-sum over sorted edges )
    const int gblk = (n * 64 + 255) / 256;
    gather_kernel<<<gblk, 256, 0, stream>>>(v, offs, counts, ssrc, h, n);

    // stage 3: out = typed_linear(h, W_a)  [bf16 in, f32 out]
    typed_mfma_bf16_f32<<<nblk, 256, 0, stream>>>(h, wt + 2 * 128 * 128, ntype, out, n);
}